// Round 17
// baseline (152.941 us; speedup 1.0000x reference)
//
#include <hip/hip_runtime.h>

#define SEQ 4096
#define DIM 1024
#define NH 16
#define HD 64
#define QKVSTR 3072

typedef __attribute__((ext_vector_type(8))) short bf16x8;
typedef __attribute__((ext_vector_type(4))) float f32x4;
typedef __attribute__((ext_vector_type(16))) float f32x16;
typedef __attribute__((ext_vector_type(4))) unsigned int uint4v;

__device__ __forceinline__ unsigned short f2bf(float f) {
  unsigned int b = __float_as_uint(f);
  b = b + 0x7fffu + ((b >> 16) & 1u);
  return (unsigned short)(b >> 16);
}

__device__ __forceinline__ unsigned int cvt_pk_bf16(float lo, float hi) {
  unsigned int r;
  asm("v_cvt_pk_bf16_f32 %0, %1, %2" : "=v"(r) : "v"(lo), "v"(hi));
  return r;
}

__device__ __forceinline__ float fast_exp2(float x) {
#if __has_builtin(__builtin_amdgcn_exp2f)
  return __builtin_amdgcn_exp2f(x);
#else
  float r; asm("v_exp_f32 %0, %1" : "=v"(r) : "v"(x)); return r;
#endif
}

typedef __attribute__((address_space(3))) unsigned int lds_uint;
typedef __attribute__((address_space(1))) const unsigned int global_uint;

__device__ __forceinline__ void gload_lds16(const void* g, void* l) {
  __builtin_amdgcn_global_load_lds((global_uint*)g, (lds_uint*)l, 16, 0, 0);
}

// ---------------- fused cast fp32 -> bf16 for all 5 tensors (1 launch) ----------------
__global__ __launch_bounds__(256) void cast_all_kernel(
    const float* __restrict__ X, const float* __restrict__ wq, const float* __restrict__ wk,
    const float* __restrict__ wv, const float* __restrict__ wo,
    unsigned short* __restrict__ Xb, unsigned short* __restrict__ Wqkv,
    unsigned short* __restrict__ Wob, float qscale) {
  int i = blockIdx.x * 256 + threadIdx.x;
  const float* src;
  unsigned short* dst;
  float sc = 1.f;
  if (i < 524288) { src = X + (size_t)i * 8; dst = Xb + (size_t)i * 8; }
  else if (i < 655360) { int j = i - 524288; src = wq + (size_t)j * 8; dst = Wqkv + (size_t)j * 8; sc = qscale; }
  else if (i < 786432) { int j = i - 655360; src = wk + (size_t)j * 8; dst = Wqkv + 1048576 + (size_t)j * 8; }
  else if (i < 917504) { int j = i - 786432; src = wv + (size_t)j * 8; dst = Wqkv + 2097152 + (size_t)j * 8; }
  else { int j = i - 917504; src = wo + (size_t)j * 8; dst = Wob + (size_t)j * 8; }
  const float4* p = (const float4*)src;
  float4 x0 = p[0], x1 = p[1];
  union { unsigned short u[8]; uint4v v; } o;
  o.u[0] = f2bf(x0.x * sc); o.u[1] = f2bf(x0.y * sc);
  o.u[2] = f2bf(x0.z * sc); o.u[3] = f2bf(x0.w * sc);
  o.u[4] = f2bf(x1.x * sc); o.u[5] = f2bf(x1.y * sc);
  o.u[6] = f2bf(x1.z * sc); o.u[7] = f2bf(x1.w * sc);
  *(uint4v*)dst = o.v;
}

// ---------------- GEMM: C[M,N] = A[M,K](bf16) @ B[N,K]^T(bf16) (+bias) ----------------
// 2-DEEP prefetch, 3 LDS buffers (R15-proven). Bijective XCD swizzle.
// BIASMODE==1 additionally writes the V section (col>=2048) TRANSPOSED into Vt.
template<int BIASMODE, int OUT_F32, int BN>
__global__ __launch_bounds__(256) void gemm_bt_kernel(
    const unsigned short* __restrict__ A, const unsigned short* __restrict__ B,
    const float* __restrict__ b0, const float* __restrict__ b1, float qscale,
    void* __restrict__ Cout, unsigned short* __restrict__ Vt, int M, int N, int K) {
  constexpr int NF = BN / 32;          // n-frags per wave
  __shared__ unsigned short As[3][128 * 32];
  __shared__ unsigned short Bs[3][BN * 32];
  int tid = threadIdx.x;
  int wave = tid >> 6, lane = tid & 63;
  int g = lane >> 4, lc = lane & 15;
  int wm = wave >> 1, wn = wave & 1;

  int gx = gridDim.x;
  int wgid = blockIdx.y * gx + blockIdx.x;
  int cpx = (gx * gridDim.y) >> 3;
  int sw = (wgid & 7) * cpx + (wgid >> 3);
  int m0 = (sw / gx) * 128, n0 = (sw % gx) * BN;

  int ch0 = wave * 64 + lane;
  int r0 = ch0 >> 2, cb0 = ch0 & 3;
  int ch1 = 256 + ch0;
  int r1 = ch1 >> 2, cb1 = ch1 & 3;
  const unsigned short* Ar0 = A + (size_t)(m0 + r0) * K + cb0 * 8;
  const unsigned short* Ar1 = A + (size_t)(m0 + r1) * K + cb1 * 8;
  const unsigned short* Br0 = B + (size_t)(n0 + r0) * K + cb0 * 8;
  const unsigned short* Br1 = B + (size_t)(n0 + r1) * K + cb1 * 8;  // unused if BN==64

  unsigned short* sAlo[3] = { &As[0][(wave * 64) * 8], &As[1][(wave * 64) * 8], &As[2][(wave * 64) * 8] };
  unsigned short* sAhi[3] = { &As[0][(256 + wave * 64) * 8], &As[1][(256 + wave * 64) * 8], &As[2][(256 + wave * 64) * 8] };
  unsigned short* sBlo[3] = { &Bs[0][(wave * 64) * 8], &Bs[1][(wave * 64) * 8], &Bs[2][(wave * 64) * 8] };
  unsigned short* sBhi[3] = { &Bs[0][(256 + wave * 64) * 8], &Bs[1][(256 + wave * 64) * 8], &Bs[2][(256 + wave * 64) * 8] };

  f32x4 acc[4][NF] = {};

  auto stage = [&](int kn, int b) {
    gload_lds16(Ar0 + kn, sAlo[b]);
    gload_lds16(Ar1 + kn, sAhi[b]);
    gload_lds16(Br0 + kn, sBlo[b]);
    if (BN == 128) gload_lds16(Br1 + kn, sBhi[b]);
  };

  auto compute = [&](int b) {
    bf16x8 af[4], bfr[NF];
    for (int mf = 0; mf < 4; ++mf)
      af[mf] = *(const bf16x8*)&As[b][(wm * 64 + mf * 16 + lc) * 32 + g * 8];
    for (int nf = 0; nf < NF; ++nf)
      bfr[nf] = *(const bf16x8*)&Bs[b][(wn * (BN / 2) + nf * 16 + lc) * 32 + g * 8];
    for (int mf = 0; mf < 4; ++mf)
      for (int nf = 0; nf < NF; ++nf)
        acc[mf][nf] = __builtin_amdgcn_mfma_f32_16x16x32_bf16(af[mf], bfr[nf], acc[mf][nf], 0, 0, 0);
  };

  const int NT = K / 32;  // 32 K-steps
  auto step = [&](int i, int CUR, int STG) {
    int kn = (i + 2 < NT) ? (i + 2) * 32 : 0;  // wrap: dummy reload of k=0
    stage(kn, STG);
    if (BN == 128) {
      asm volatile("s_waitcnt vmcnt(8)" ::: "memory");   // tile i resident; i+1,i+2 in flight
    } else {
      asm volatile("s_waitcnt vmcnt(6)" ::: "memory");
    }
    __builtin_amdgcn_sched_barrier(0);
    __builtin_amdgcn_s_barrier();
    __builtin_amdgcn_sched_barrier(0);
    compute(CUR);
    asm volatile("" ::: "memory");
    __builtin_amdgcn_sched_barrier(0);
    __builtin_amdgcn_s_barrier();   // reads of tile i done -> buf may be overwritten next iter
  };

  stage(0, 0);
  stage(32, 1);

  for (int ii = 0; ii < 30; ii += 3) {
    step(ii + 0, 0, 2);
    step(ii + 1, 1, 0);
    step(ii + 2, 2, 1);
  }
  step(30, 0, 2);
  step(31, 1, 0);

  for (int nf = 0; nf < NF; ++nf) {
    int col = n0 + wn * (BN / 2) + nf * 16 + lc;
    float bias = 0.f;
    if (BIASMODE == 1) {
      int sect = col >> 10, cc = col & 1023;
      bias = (sect == 0) ? b0[cc] * qscale : ((sect == 2) ? b1[cc] : 0.f);
    } else if (BIASMODE == 2) {
      bias = b0[col];
    }
    for (int mf = 0; mf < 4; ++mf) {
      int row = m0 + wm * 64 + mf * 16 + g * 4;
      for (int r = 0; r < 4; ++r) {
        float v = acc[mf][nf][r] + bias;
        if (OUT_F32) {
          ((float*)Cout)[(size_t)(row + r) * N + col] = v;
        } else if (BIASMODE == 1 && col >= 2048) {
          Vt[(size_t)(col - 2048) * SEQ + row + r] = f2bf(v);
        } else {
          ((unsigned short*)Cout)[(size_t)(row + r) * N + col] = f2bf(v);
        }
      }
    }
  }
}

// ---------------- flash attention: 8-wave kv-split, KVBLK=32, 48KB LDS (3 blocks/CU) ----------------
// R16-proven structure. V swizzle widened: g(r) = (r&3)^((r>>2)&3) -> 4-way
// bank conflicts on PV reads (was 8-way with plain r&3). Same involution on
// staging source and read side (rule #21). g(l31+32)==g(l31) keeps vf1's +2048B.
__global__ __launch_bounds__(512, 1) void attn_kernel(
    const unsigned short* __restrict__ QKV, const unsigned short* __restrict__ Vt,
    unsigned short* __restrict__ Aout) {
  __shared__ unsigned short SMEM[24576];  // 48 KB
  unsigned short* Qs = SMEM;                                   // 8192 elems
  int tid = threadIdx.x;
  int w = tid >> 6, lane = tid & 63;
  int hi = lane >> 5, l31 = lane & 31;
  int qw = w & 3, grp = w >> 2;

  // XCD swizzle: 512 blocks, 8 XCDs -> XCD x owns heads 2x..2x+1 (K/V fit 4MB L2)
  int bid = blockIdx.x;
  int swz = (bid & 7) * 64 + (bid >> 3);
  int h = swz >> 5;
  int q0 = (swz & 31) * 128;

  const unsigned short* Qg = QKV + h * HD;
  const unsigned short* Kg = QKV + DIM + h * HD;
  const unsigned short* Vg = Vt + (size_t)(h * HD) * SEQ;
  int kvbase = grp * (SEQ / 2);

  // per-group LDS tile bases (elems): K tile 2048 (32x64), V tile 2048 (64x32)
  unsigned short* Kt0 = SMEM + 8192 + (grp * 2 + 0) * 2048;
  unsigned short* Kt1 = SMEM + 8192 + (grp * 2 + 1) * 2048;
  unsigned short* Vt0 = SMEM + 16384 + (grp * 2 + 0) * 2048;
  unsigned short* Vt1 = SMEM + 16384 + (grp * 2 + 1) * 2048;

  // staging: 256 chunks per tile, 1 chunk/lane (ch = qw*64+lane)
  int ch = qw * 64 + lane;
  int krow = ch >> 3, kpos = (ch & 7) ^ (krow & 7);                          // K: 128B rows, XOR-8
  int vrow = ch >> 2;
  int vpos = (ch & 3) ^ (vrow & 3) ^ ((vrow >> 2) & 3);                      // V: 64B rows, widened g(r)
  size_t koff = (size_t)krow * QKVSTR + kpos * 8;
  size_t voff = (size_t)vrow * SEQ + vpos * 8;
  unsigned short* sKb[2] = { Kt0 + (qw * 64) * 8, Kt1 + (qw * 64) * 8 };
  unsigned short* sVb[2] = { Vt0 + (qw * 64) * 8, Vt1 + (qw * 64) * 8 };

  // stage Q [128][64]: 1024 chunks by 8 waves, XOR-8 swizzled via global source
  for (int c = 0; c < 2; ++c) {
    int chunk = c * 512 + w * 64 + lane;
    int row = chunk >> 3, pos = chunk & 7;
    int db = pos ^ (row & 7);
    gload_lds16(Qg + (size_t)(q0 + row) * QKVSTR + db * 8, Qs + (c * 512 + w * 64) * 8);
  }
  // stage this group's K/V tile 0 (2 loads)
  gload_lds16(Kg + (size_t)kvbase * QKVSTR + koff, sKb[0]);
  gload_lds16(Vg + kvbase + voff, sVb[0]);
  asm volatile("s_waitcnt vmcnt(2)" ::: "memory");  // Q landed; tile0 in flight
  __builtin_amdgcn_sched_barrier(0);
  __builtin_amdgcn_s_barrier();

  // Q fragments (B-operand: col q = l31, k = d); both groups read same q-rows
  bf16x8 qf[4];
  {
    int qrow = qw * 32 + l31;
    for (int dc = 0; dc < 4; ++dc) {
      int pos = 2 * dc + hi;
      qf[dc] = *(const bf16x8*)&Qs[qrow * 64 + (pos ^ (qrow & 7)) * 8];
    }
  }

  // hoisted LDS byte offsets
  int kOffb[4], vOffb[2];
#pragma unroll
  for (int dc = 0; dc < 4; ++dc)
    kOffb[dc] = l31 * 128 + (((2 * dc + hi) ^ (l31 & 7)) * 16);
  int gv = (l31 & 3) ^ ((l31 >> 2) & 3);
#pragma unroll
  for (int c = 0; c < 2; ++c)
    vOffb[c] = l31 * 64 + (((2 * c + hi) ^ gv) * 16);
  const char* KbA = (const char*)Kt0;
  const char* KbB = (const char*)Kt1;
  const char* VbA = (const char*)Vt0;
  const char* VbB = (const char*)Vt1;

  f32x16 o0 = {}, o1 = {};
  float la0 = 0.f, la1 = 0.f, la2 = 0.f, la3 = 0.f;

  auto body = [&](int t, int CUR) {
    int NB = CUR ^ 1;
    int kvn = kvbase + (((t + 1) & 63) << 5);
    gload_lds16(Kg + (size_t)kvn * QKVSTR + koff, sKb[NB]);
    gload_lds16(Vg + kvn + voff, sVb[NB]);
    asm volatile("s_waitcnt vmcnt(2)" ::: "memory");  // tile t resident (this wave)
    __builtin_amdgcn_sched_barrier(0);
    __builtin_amdgcn_s_barrier();                     // tile t resident (all waves)
    __builtin_amdgcn_sched_barrier(0);

    const char* Kb = CUR ? KbB : KbA;
    const char* Vb = CUR ? VbB : VbA;
    bf16x8 kf[4];
#pragma unroll
    for (int dc = 0; dc < 4; ++dc)
      kf[dc] = *(const bf16x8*)(Kb + kOffb[dc]);
    f32x16 st0 = {};
    __builtin_amdgcn_s_setprio(1);
#pragma unroll
    for (int dc = 0; dc < 4; ++dc)
      st0 = __builtin_amdgcn_mfma_f32_32x32x16_bf16(kf[dc], qf[dc], st0, 0, 0, 0);
    __builtin_amdgcn_s_setprio(0);

    // V fragments early (latency hides under exp/pack)
    bf16x8 vf0[2], vf1[2];
#pragma unroll
    for (int c = 0; c < 2; ++c) {
      vf0[c] = *(const bf16x8*)(Vb + vOffb[c]);
      vf1[c] = *(const bf16x8*)(Vb + vOffb[c] + 2048);
    }

    // P = exp2(S^T); 4 independent lsum accumulators
    float p0[16];
#pragma unroll
    for (int r = 0; r < 16; r += 4) {
      p0[r] = fast_exp2(st0[r]); p0[r + 1] = fast_exp2(st0[r + 1]);
      p0[r + 2] = fast_exp2(st0[r + 2]); p0[r + 3] = fast_exp2(st0[r + 3]);
      la0 += p0[r]; la1 += p0[r + 1]; la2 += p0[r + 2]; la3 += p0[r + 3];
    }

    // pack to bf16 + permlane32_swap -> PV A-frags pa[0..1] (T12)
    bf16x8 pa[2];
#pragma unroll
    for (int cc = 0; cc < 2; ++cc) {
      unsigned uLO0 = cvt_pk_bf16(p0[8 * cc + 0], p0[8 * cc + 1]);
      unsigned uLO1 = cvt_pk_bf16(p0[8 * cc + 2], p0[8 * cc + 3]);
      unsigned uHI0 = cvt_pk_bf16(p0[8 * cc + 4], p0[8 * cc + 5]);
      unsigned uHI1 = cvt_pk_bf16(p0[8 * cc + 6], p0[8 * cc + 7]);
      auto s0 = __builtin_amdgcn_permlane32_swap(uLO0, uHI0, false, false);
      auto s1 = __builtin_amdgcn_permlane32_swap(uLO1, uHI1, false, false);
      union { unsigned u[4]; bf16x8 v; } pw;
      pw.u[0] = s0[0]; pw.u[1] = s1[0]; pw.u[2] = s0[1]; pw.u[3] = s1[1];
      pa[cc] = pw.v;
    }

    // PV
    __builtin_amdgcn_s_setprio(1);
#pragma unroll
    for (int c = 0; c < 2; ++c) {
      o0 = __builtin_amdgcn_mfma_f32_32x32x16_bf16(pa[c], vf0[c], o0, 0, 0, 0);
      o1 = __builtin_amdgcn_mfma_f32_32x32x16_bf16(pa[c], vf1[c], o1, 0, 0, 0);
    }
    __builtin_amdgcn_s_setprio(0);

    asm volatile("" ::: "memory");
    __builtin_amdgcn_sched_barrier(0);
    __builtin_amdgcn_s_barrier();   // reads of tile t done -> next stage may overwrite
  };

  for (int tt = 0; tt < 64; tt += 2) {
    body(tt + 0, 0);
    body(tt + 1, 1);
  }

  // per-half lsum finalize (cross-hi reduce)
  float lsum = (la0 + la1) + (la2 + la3);
  lsum += __shfl_xor(lsum, 32);

  // combine halves (exact; two passes through 32KB region)
  float* cb = (float*)SMEM;               // 8192 floats
  float* cbL = (float*)(SMEM + 16384);    // 256 floats
  int cbase = (qw * 64 + lane) * 32;
  int lx = lane & 31;
  __syncthreads();  // drains wrap-prefetch vmcnt; all tile reads done
  if (grp == 1) {
#pragma unroll
    for (int r = 0; r < 16; ++r) cb[cbase + (r ^ lx)] = o0[r];
    cbL[qw * 64 + lane] = lsum;
  }
  __syncthreads();
  if (grp == 0) {
#pragma unroll
    for (int r = 0; r < 16; ++r) o0[r] += cb[cbase + (r ^ lx)];
    lsum += cbL[qw * 64 + lane];
  }
  __syncthreads();
  if (grp == 1) {
#pragma unroll
    for (int r = 0; r < 16; ++r) cb[cbase + (r ^ lx)] = o1[r];
  }
  __syncthreads();
  if (grp == 0) {
#pragma unroll
    for (int r = 0; r < 16; ++r) o1[r] += cb[cbase + (r ^ lx)];
    float inv = 1.f / lsum;
#pragma unroll
    for (int r = 0; r < 16; ++r) {
      int qr = (r & 3) + 8 * (r >> 2) + 4 * hi;
      float ir = __shfl(inv, qr + (lane & 32));
      size_t row = q0 + qw * 32 + qr;
      Aout[row * DIM + h * HD + l31]      = f2bf(o0[r] * ir);
      Aout[row * DIM + h * HD + 32 + l31] = f2bf(o1[r] * ir);
    }
  }
}

extern "C" void kernel_launch(void* const* d_in, const int* in_sizes, int n_in,
                              void* d_out, int out_size, void* d_ws, size_t ws_size,
                              hipStream_t stream) {
  (void)in_sizes; (void)n_in; (void)out_size; (void)ws_size;
  const float* X  = (const float*)d_in[0];
  const float* wq = (const float*)d_in[1];
  const float* bq = (const float*)d_in[2];
  const float* wk = (const float*)d_in[3];
  const float* wv = (const float*)d_in[4];
  const float* bv = (const float*)d_in[5];
  const float* wo = (const float*)d_in[6];
  const float* bo = (const float*)d_in[7];

  char* ws = (char*)d_ws;
  const size_t SZ_XD  = (size_t)SEQ * DIM * 2;      // 8 MB
  const size_t SZ_W   = (size_t)DIM * DIM * 2;      // 2 MB
  const size_t SZ_QKV = (size_t)SEQ * QKVSTR * 2;   // 24 MB
  unsigned short* Xb   = (unsigned short*)(ws);                    // reused as Ab
  unsigned short* Wqkv = (unsigned short*)(ws + SZ_XD);            // [3072][1024]
  unsigned short* Wob  = (unsigned short*)(ws + SZ_XD + 3 * SZ_W);
  unsigned short* QKVb = (unsigned short*)(ws + SZ_XD + 4 * SZ_W); // [4096][3072]
  unsigned short* Vtb  = (unsigned short*)(ws + SZ_XD + 4 * SZ_W + SZ_QKV);
  unsigned short* Ab   = Xb;

  const float QSCALE = 0.125f * 1.44269504088896f;  // fold 1/sqrt(hd) * log2(e) into Wq/bq

  // one fused cast launch: 1048576 groups of 8 -> 4096 blocks
  cast_all_kernel<<<4096, 256, 0, stream>>>(X, wq, wk, wv, wo, Xb, Wqkv, Wob, QSCALE);

  // fused QKV projection: [4096][3072] bf16; V section written transposed to Vtb
  gemm_bt_kernel<1, 0, 128><<<dim3(QKVSTR / 128, SEQ / 128), 256, 0, stream>>>(
      Xb, Wqkv, bq, bv, QSCALE, QKVb, Vtb, SEQ, QKVSTR, DIM);

  attn_kernel<<<SEQ / 128 * NH, 512, 0, stream>>>(QKVb, Vtb, Ab);

  // output projection (f32 out): 128x64 tiles -> 512 blocks = 2/CU
  gemm_bt_kernel<2, 1, 64><<<dim3(DIM / 64, SEQ / 128), 256, 0, stream>>>(
      Ab, Wob, bo, nullptr, 1.f, d_out, nullptr, SEQ, DIM, DIM);
}